// Round 5
// baseline (231.831 us; speedup 1.0000x reference)
//
#include <hip/hip_runtime.h>
#include <hip/hip_bf16.h>

// Problem constants
#define EDIM 1024
#define TDIM 2048
#define MTOT 32768   // B*T = 16*2048
#define VCAP 8192    // vocab 8000 padded to 8192 for 128-row GEMM tiles

typedef __attribute__((ext_vector_type(8))) short short8;
typedef __attribute__((ext_vector_type(8))) unsigned short ushort8;
typedef __attribute__((ext_vector_type(4))) float f32x4;

__device__ __forceinline__ ushort f2bf(float f) {
  unsigned u = __float_as_uint(f);
  u += 0x7fff + ((u >> 16) & 1);   // RNE
  return (ushort)(u >> 16);
}

// global -> LDS direct DMA, 16B per lane. LDS dest is wave-uniform base +
// lane*16 (guide m104/m108); global src is per-lane.
__device__ __forceinline__ void gld16(const void* g, void* l) {
  __builtin_amdgcn_global_load_lds(
      (const __attribute__((address_space(1))) void*)g,
      (__attribute__((address_space(3))) void*)l, 16, 0, 0);
}

// Non-temporal 16B store. __builtin_nontemporal_store requires a native
// scalar/ext-vector pointee (HIP_vector_type float4* is rejected) -> f32x4.
__device__ __forceinline__ void nt_store(float* p, float4 v) {
  f32x4 x = {v.x, v.y, v.z, v.w};
  __builtin_nontemporal_store(x, (f32x4*)p);
}

// ---------------------------------------------------------------------------
// Algebraic plan:
//   mid[m] = (1/24) * sum_c s_c(m) * embed[tok_c],  s_c = <embed[tok_c], Psum_c>
//   y[m]   = (1/24) * sum_c s_c * EW[tok_c] + b,    EW[v] = embed[v] @ W^T
//   out[m] = swish(LN(y[m]))
// Pipeline: prep(Psum,Wb) -> dcvt(Ebf,D) -> gemm(EW) -> final(out)
// ---------------------------------------------------------------------------

// ---------------------------------------------------------------------------
// K0: merged prep. Blocks 0..1023: Wb = bf16(ffn_w) (1M elems).
//     Blocks 1024..1035: Psum[c][e] = sum_h pos_w[h,e,c].
// ---------------------------------------------------------------------------
__global__ __launch_bounds__(256) void prep_kernel(
    const float* __restrict__ pos_w, const float* __restrict__ W,
    float* __restrict__ Psum, ushort* __restrict__ Wb) {
  int b = blockIdx.x;
  if (b < 1024) {
    int i = (b * 256 + threadIdx.x) << 2;
    float4 v = *(const float4*)&W[i];
    ushort4 o;
    o.x = f2bf(v.x); o.y = f2bf(v.y); o.z = f2bf(v.z); o.w = f2bf(v.w);
    *(ushort4*)&Wb[i] = o;
  } else {
    int idx = (b - 1024) * 256 + threadIdx.x;     // 0..3071
    int c = idx >> 10, e = idx & 1023;
    float s = 0.f;
#pragma unroll
    for (int h = 0; h < 8; ++h) s += pos_w[h * (EDIM * 3) + e * 3 + c];
    Psum[idx] = s;                                // layout Psum[c*1024 + e]
  }
}

// ---------------------------------------------------------------------------
// K1: per vocab row v: Ebf[v] = bf16(embed[v]);  D[v][c] = <embed[v], Psum_c>.
// One block per row, 256 threads x 4 elems. Rows >= 8000 zeroed (GEMM padding;
// never gathered since tokens < 8000).
// ---------------------------------------------------------------------------
__global__ __launch_bounds__(256) void dcvt_kernel(
    const float* __restrict__ embed, const float* __restrict__ Psum,
    ushort* __restrict__ Ebf, float* __restrict__ D) {
  int v = blockIdx.x;                  // 0..8191
  int tid = threadIdx.x;
  int e4 = tid << 2;
  if (v >= 8000) {
    ushort4 z; z.x = z.y = z.z = z.w = 0;
    *(ushort4*)&Ebf[(size_t)v * EDIM + e4] = z;
    if (tid < 4) D[v * 4 + tid] = 0.f;
    return;
  }
  float4 r = *(const float4*)&embed[(size_t)v * EDIM + e4];
  ushort4 o;
  o.x = f2bf(r.x); o.y = f2bf(r.y); o.z = f2bf(r.z); o.w = f2bf(r.w);
  *(ushort4*)&Ebf[(size_t)v * EDIM + e4] = o;

  float4 q0 = *(const float4*)&Psum[0 * EDIM + e4];
  float4 q1 = *(const float4*)&Psum[1 * EDIM + e4];
  float4 q2 = *(const float4*)&Psum[2 * EDIM + e4];
  float p0 = r.x * q0.x + r.y * q0.y + r.z * q0.z + r.w * q0.w;
  float p1 = r.x * q1.x + r.y * q1.y + r.z * q1.z + r.w * q1.w;
  float p2 = r.x * q2.x + r.y * q2.y + r.z * q2.z + r.w * q2.w;
#pragma unroll
  for (int off = 32; off; off >>= 1) {
    p0 += __shfl_xor(p0, off);
    p1 += __shfl_xor(p1, off);
    p2 += __shfl_xor(p2, off);
  }
  __shared__ float red[4][3];
  int wv = tid >> 6, ln = tid & 63;
  if (ln == 0) { red[wv][0] = p0; red[wv][1] = p1; red[wv][2] = p2; }
  __syncthreads();
  if (tid < 3) {
    D[v * 4 + tid] = (red[0][tid] + red[1][tid]) + (red[2][tid] + red[3][tid]);
  }
}

// ---------------------------------------------------------------------------
// K2: EW[v,n] = sum_k Ebf[v,k]*Wb[n,k]   (gemm_bt, bf16 MFMA, f32 out, NO bias)
// m97 structure [guide §5 step 3]: global_load_lds dwordx4 staging, 128x128
// tile, BK=32, 4 waves each 64x64 (4x4 of 16x16x32). M=8192 -> grid (8,64),
// nwg=512 %8==0 -> bijective XCD-chunked swizzle (CPX=64).
// EPILOGUE (R4): operands SWAPPED in the MFMA -> output fragment transposed:
// thread holds col(=m)=lane&15 fixed and row(=n)=(lane>>4)*4+reg consecutive,
// so the C-write is 16x global_store_dwordx4 instead of 64x scalar dword.
// Numerically identical (A/B fragment layouts are operand-role symmetric,
// guide m89/m91).
// ---------------------------------------------------------------------------
__global__ __launch_bounds__(256) void gemm_kernel(
    const ushort* __restrict__ A, const ushort* __restrict__ Wb,
    float* __restrict__ out) {
  __shared__ ushort As[128 * 32];
  __shared__ ushort Bs[128 * 32];
  int tid = threadIdx.x;
  int wave = tid >> 6, lane = tid & 63;

  // XCD-chunked swizzle (nwg = 512, divisible by 8 -> bijective; CPX = 64)
  int linear = (blockIdx.y << 3) | blockIdx.x;
  int swz = ((linear & 7) << 6) | (linear >> 3);
  int tileM = (swz >> 3) << 7;
  int tileN = (swz & 7) << 7;

  int wm = (wave >> 1) << 6;
  int wn = (wave & 1) << 6;

  f32x4 acc[4][4];
#pragma unroll
  for (int i = 0; i < 4; ++i)
#pragma unroll
    for (int j = 0; j < 4; ++j) acc[i][j] = (f32x4){0.f, 0.f, 0.f, 0.f};

  // staging addresses: wave w stages 32 rows of each operand as 2x1024B chunks
  int sr = lane >> 2;            // 0..15 row within chunk
  int sc = (lane & 3) << 3;      // elem col 0,8,16,24
  const ushort* Ap = A  + (size_t)(tileM + (wave << 5) + sr) * EDIM + sc;
  const ushort* Bp = Wb + (size_t)(tileN + (wave << 5) + sr) * EDIM + sc;
  ushort* aDst = &As[(wave << 1) * 512];   // 1024B chunk base (wave-uniform)
  ushort* bDst = &Bs[(wave << 1) * 512];

  int arow = lane & 15;
  int kq = (lane >> 4) << 3;

  for (int k0 = 0; k0 < EDIM; k0 += 32) {
    gld16(Ap + k0, aDst);
    gld16(Ap + (size_t)16 * EDIM + k0, aDst + 512);
    gld16(Bp + k0, bDst);
    gld16(Bp + (size_t)16 * EDIM + k0, bDst + 512);
    __syncthreads();   // compiler emits s_waitcnt vmcnt(0) lgkmcnt(0) first

    short8 af[4], bfv[4];
#pragma unroll
    for (int i = 0; i < 4; ++i) {
      af[i]  = *(const short8*)&As[(wm + i * 16 + arow) * 32 + kq];
      bfv[i] = *(const short8*)&Bs[(wn + i * 16 + arow) * 32 + kq];
    }
#pragma unroll
    for (int i = 0; i < 4; ++i)
#pragma unroll
      for (int j = 0; j < 4; ++j)
        acc[i][j] = __builtin_amdgcn_mfma_f32_16x16x32_bf16(bfv[j], af[i], acc[i][j], 0, 0, 0);
    __syncthreads();
  }

  // Transposed-fragment epilogue: m = lane&15 (fixed), n = rq + 4 consecutive
  int m_off = lane & 15, rq = (lane >> 4) << 2;
#pragma unroll
  for (int i = 0; i < 4; ++i) {
    int row = tileM + wm + i * 16 + m_off;
#pragma unroll
    for (int j = 0; j < 4; ++j) {
      int nb = tileN + wn + j * 16 + rq;
      *(f32x4*)&out[(size_t)row * EDIM + nb] = acc[i][j];   // cached: final re-reads EW
    }
  }
}

// ---------------------------------------------------------------------------
// K3: final fused kernel, 8 TOKENS PER BLOCK (window overlap exploitation):
// consecutive tokens share 2/3 gather rows -> 10 row-loads instead of 24.
// All window scalars (idx, s_c) depend only on blockIdx -> SGPRs.
// Output stores are NON-TEMPORAL (write-once stream; keeps EW hot in L3).
// ---------------------------------------------------------------------------
__global__ __launch_bounds__(256) void final_kernel(
    const int* __restrict__ tokens, const float* __restrict__ EW,
    const float* __restrict__ D, const float* __restrict__ bias,
    const float* __restrict__ g, const float* __restrict__ bta,
    float* __restrict__ out) {
  int m0 = blockIdx.x << 3;
  int t0 = m0 & (TDIM - 1);
  int tid = threadIdx.x;
  int e4 = tid << 2;

  // uniform (SGPR) window data
  int idx[10];
#pragma unroll
  for (int j = 0; j < 10; ++j) {
    int mm = m0 - 2 + j;
    idx[j] = tokens[mm < 0 ? 0 : mm];
  }
  const float inv = 1.0f / 24.0f;
  float s0[8], s1[8], s2[8];
#pragma unroll
  for (int j = 0; j < 8; ++j) {
    int t = t0 + j;
    s2[j] = D[idx[j + 2] * 4 + 2] * inv;
    s1[j] = (t >= 1) ? D[idx[j + 1] * 4 + 1] * inv : 0.f;
    s0[j] = (t >= 2) ? D[idx[j] * 4 + 0] * inv : 0.f;
  }

  // gather the 10 distinct window rows (per-thread float4 slices)
  float4 r[10];
#pragma unroll
  for (int j = 0; j < 10; ++j)
    r[j] = *(const float4*)&EW[(size_t)idx[j] * EDIM + e4];

  float4 bb = *(const float4*)&bias[e4];
  float4 y[8];
  float sred[8], qred[8];
#pragma unroll
  for (int j = 0; j < 8; ++j) {
    float4 v;
    v.x = s0[j] * r[j].x + s1[j] * r[j + 1].x + s2[j] * r[j + 2].x + bb.x;
    v.y = s0[j] * r[j].y + s1[j] * r[j + 1].y + s2[j] * r[j + 2].y + bb.y;
    v.z = s0[j] * r[j].z + s1[j] * r[j + 1].z + s2[j] * r[j + 2].z + bb.z;
    v.w = s0[j] * r[j].w + s1[j] * r[j + 1].w + s2[j] * r[j + 2].w + bb.w;
    y[j] = v;
    sred[j] = (v.x + v.y) + (v.z + v.w);
    qred[j] = (v.x * v.x + v.y * v.y) + (v.z * v.z + v.w * v.w);
  }

#pragma unroll
  for (int off = 32; off; off >>= 1) {
#pragma unroll
    for (int j = 0; j < 8; ++j) {
      sred[j] += __shfl_xor(sred[j], off);
      qred[j] += __shfl_xor(qred[j], off);
    }
  }
  __shared__ float red[4][8][2];
  int wv = tid >> 6, ln = tid & 63;
  if (ln == 0) {
#pragma unroll
    for (int j = 0; j < 8; ++j) {
      red[wv][j][0] = sred[j];
      red[wv][j][1] = qred[j];
    }
  }
  __syncthreads();

  float4 gg = *(const float4*)&g[e4];
  float4 b2 = *(const float4*)&bta[e4];
#pragma unroll
  for (int j = 0; j < 8; ++j) {
    float S = (red[0][j][0] + red[1][j][0]) + (red[2][j][0] + red[3][j][0]);
    float Q = (red[0][j][1] + red[1][j][1]) + (red[2][j][1] + red[3][j][1]);
    float mu = S * (1.0f / EDIM);
    float var = Q * (1.0f / EDIM) - mu * mu;
    float rs = rsqrtf(var + 1e-5f);
    float x0 = (y[j].x - mu) * rs * gg.x + b2.x;
    float x1 = (y[j].y - mu) * rs * gg.y + b2.y;
    float x2 = (y[j].z - mu) * rs * gg.z + b2.z;
    float x3 = (y[j].w - mu) * rs * gg.w + b2.w;
    float4 o;
    o.x = x0 / (1.f + expf(-x0));
    o.y = x1 / (1.f + expf(-x1));
    o.z = x2 / (1.f + expf(-x2));
    o.w = x3 / (1.f + expf(-x3));
    nt_store(&out[(size_t)(m0 + j) * EDIM + e4], o);
  }
}

// ---------------------------------------------------------------------------
// Buffer plan (ws usage < 51 MiB):
//   ws[ 0M : 16M)        Ebf   bf16 embed, 8192x1024 (dcvt -> gemm)
//   ws[16M : 48M)        EW    f32 embed@W^T, 8192x1024 (gemm -> final)
//   ws[48M : 50M)        Wb    bf16 ffn_w (prep -> gemm)
//   ws[50M : 50M+12K)    Psum  (prep -> dcvt)
//   ws[50M+16K : +128K)  D     f32 [8192][4] (dcvt -> final)
// OUTPUT IS F32 (reference output dtype = float32).
// ---------------------------------------------------------------------------
extern "C" void kernel_launch(void* const* d_in, const int* in_sizes, int n_in,
                              void* d_out, int out_size, void* d_ws, size_t ws_size,
                              hipStream_t stream) {
  const int*   tokens = (const int*)d_in[0];
  const float* embed  = (const float*)d_in[1];
  const float* pos_w  = (const float*)d_in[2];
  const float* ffn_w  = (const float*)d_in[3];
  const float* ffn_b  = (const float*)d_in[4];
  const float* ln_g   = (const float*)d_in[5];
  const float* ln_b   = (const float*)d_in[6];

  char* ws = (char*)d_ws;
  const size_t MB = 1024 * 1024;
  ushort* Ebf  = (ushort*)ws;                          // 16 MiB
  float*  EW   = (float*)(ws + 16 * MB);               // 32 MiB
  ushort* Wb   = (ushort*)(ws + 48 * MB);              // 2 MiB
  float*  Psum = (float*)(ws + 50 * MB);               // 12 KiB
  float*  D    = (float*)(ws + 50 * MB + 16 * 1024);   // 128 KiB
  float*  outp = (float*)d_out;                        // f32 output

  prep_kernel<<<1036, 256, 0, stream>>>(pos_w, ffn_w, Psum, Wb);
  dcvt_kernel<<<VCAP, 256, 0, stream>>>(embed, Psum, Ebf, D);
  dim3 g2(8, 64);
  gemm_kernel<<<g2, 256, 0, stream>>>(Ebf, Wb, EW);
  final_kernel<<<MTOT / 8, 256, 0, stream>>>(tokens, EW, D, ffn_b, ln_g, ln_b, outp);
}